// Round 7
// baseline (759.683 us; speedup 1.0000x reference)
//
#include <hip/hip_runtime.h>
#include <hip/hip_bf16.h>
#include <math.h>

// Problem constants (from reference)
#define NN 50000
#define EE 800000
#define FIN 256
#define DD 150
#define HC 300        // H*C
#define CC 150
#define ET (EE + NN)  // edges + self loops = 850000
#define LN_EPS 1e-5f
#define NT 19         // col tiles of 16 covering 300 (304)

typedef __attribute__((ext_vector_type(8))) short short8;   // 8 bf16 (4 VGPR)
typedef __attribute__((ext_vector_type(4))) float f32x4;    // MFMA C/D frag
typedef unsigned short u16;
typedef unsigned int u32;

static __device__ __forceinline__ u16 f2bf(float f) {
  u32 u = __float_as_uint(f);
  u += 0x7FFFu + ((u >> 16) & 1u);   // round-to-nearest-even
  return (u16)(u >> 16);
}
static __device__ __forceinline__ float bflo(u32 u) {
  return __uint_as_float(u << 16);
}
static __device__ __forceinline__ float bfhi(u32 u) {
  return __uint_as_float(u & 0xFFFF0000u);
}

// ---------------------------------------------------------------------------
// k1: idx = argmax(x, axis=1); h0b = bf16(emb[idx])   (one wave per node)
// ---------------------------------------------------------------------------
__global__ __launch_bounds__(256) void k_argmax_embed(
    const float* __restrict__ x, const float* __restrict__ emb,
    u16* __restrict__ h0b) {
  int node = blockIdx.x * 4 + (threadIdx.x >> 6);
  int lane = threadIdx.x & 63;
  if (node >= NN) return;
  const float* row = x + (size_t)node * FIN;
  float best = -INFINITY;
  int bidx = FIN;
  #pragma unroll
  for (int r = 0; r < FIN / 64; ++r) {
    int j = lane + 64 * r;
    float v = row[j];
    if (v > best || (v == best && j < bidx)) { best = v; bidx = j; }
  }
  #pragma unroll
  for (int off = 32; off > 0; off >>= 1) {
    float ov = __shfl_xor(best, off, 64);
    int   oi = __shfl_xor(bidx, off, 64);
    if (ov > best || (ov == best && oi < bidx)) { best = ov; bidx = oi; }
  }
  // 150 f32 -> 75 uints of 2 bf16
  const float2* e2 = (const float2*)(emb + (size_t)bidx * DD);
  u32* o = (u32*)(h0b + (size_t)node * DD);
  float2 v = e2[lane];
  o[lane] = (u32)f2bf(v.x) | ((u32)f2bf(v.y) << 16);
  if (lane < 11) {
    float2 w = e2[64 + lane];
    o[64 + lane] = (u32)f2bf(w.x) | ((u32)f2bf(w.y) << 16);
  }
}

// ---------------------------------------------------------------------------
// CSR build (count / scan / scatter)
// ---------------------------------------------------------------------------
__global__ __launch_bounds__(256) void k_count(
    const int* __restrict__ ei, int* __restrict__ counts) {
  int et = blockIdx.x * blockDim.x + threadIdx.x;
  if (et >= ET) return;
  int d = (et < EE) ? ei[EE + et] : (et - EE);
  atomicAdd(&counts[d], 1);
}

__global__ __launch_bounds__(1024) void k_scan(
    const int* __restrict__ counts, int* __restrict__ offsets) {
  __shared__ int buf[1024];
  const int CH = 49;  // 1024*49 >= NN
  int tid = threadIdx.x;
  int base = tid * CH;
  int lsum = 0;
  for (int c = 0; c < CH; ++c) {
    int i = base + c;
    if (i < NN) lsum += counts[i];
  }
  buf[tid] = lsum;
  __syncthreads();
  for (int off = 1; off < 1024; off <<= 1) {
    int t = (tid >= off) ? buf[tid - off] : 0;
    __syncthreads();
    buf[tid] += t;
    __syncthreads();
  }
  int incl = buf[tid];
  int run = incl - lsum;
  for (int c = 0; c < CH; ++c) {
    int i = base + c;
    if (i < NN) { offsets[i] = run; run += counts[i]; }
  }
  if (tid == 1023) offsets[NN] = incl;
}

__global__ __launch_bounds__(256) void k_scatter(
    const int* __restrict__ ei, const int* __restrict__ offsets,
    int* __restrict__ cursor, int* __restrict__ csr_src) {
  int et = blockIdx.x * blockDim.x + threadIdx.x;
  if (et >= ET) return;
  int s = (et < EE) ? ei[et] : (et - EE);
  int d = (et < EE) ? ei[EE + et] : (et - EE);
  int pos = offsets[d] + atomicAdd(&cursor[d], 1);
  csr_src[pos] = s;
}

// ---------------------------------------------------------------------------
// k_pack_w: W [K][300] f32 -> Wp bf16 B-fragment layout [ks][ct][lane][8]
// Wp[((ks*NT+ct)*64+l)*8 + j] = W[ks*32+(l>>4)*8+j][ct*16+(l&15)]
// ---------------------------------------------------------------------------
__global__ __launch_bounds__(64) void k_pack_w(
    const float* __restrict__ W, u16* __restrict__ Wp, int K) {
  int ks = blockIdx.x / NT, ct = blockIdx.x % NT;
  int l = threadIdx.x;
  int col = ct * 16 + (l & 15);
  int kb = ks * 32 + ((l >> 4) << 3);
  u16 v[8];
  #pragma unroll
  for (int j = 0; j < 8; ++j) {
    int k = kb + j;
    float f = (k < K && col < HC) ? W[(size_t)k * HC + col] : 0.f;
    v[j] = f2bf(f);
  }
  *(ulonglong2*)(Wp + ((size_t)blockIdx.x * 64 + l) * 8) = *(ulonglong2*)v;
}

// ---------------------------------------------------------------------------
// k_gemm_mfma: hp(bf16) = h(bf16) @ W via mfma_f32_16x16x32_bf16, with fused
// attention-coefficient epilogue writing al_s/al_d (f32, from f32 acc).
// Block 256 = 4 waves, 64 rows/block; wave w -> rows [w*16, w*16+16).
// ---------------------------------------------------------------------------
template <int K>
__global__ __launch_bounds__(256) void k_gemm_mfma(
    const u16* __restrict__ h, const u16* __restrict__ Wp,
    const float* __restrict__ a_s, const float* __restrict__ a_d,
    u16* __restrict__ hpb, float* __restrict__ al_s,
    float* __restrict__ al_d) {
  constexpr int KS = (K + 31) / 32;
  constexpr int RS = KS * 32 + 8;     // +8 shorts pad
  constexpr int KU = K / 2;           // uints per row (K even)
  constexpr int ZU = (KS * 32 - K) / 2;
  __shared__ u16 sh[64 * RS];
  int tid = threadIdx.x;
  int wave = tid >> 6, lane = tid & 63;
  int rows0 = blockIdx.x * 64;

  // stage h (already bf16) -> LDS
  const u32* hu = (const u32*)h;
  for (int i = tid; i < 64 * KU; i += 256) {
    int r = i / KU, c = i - r * KU;
    int gr = rows0 + r; if (gr >= NN) gr = NN - 1;
    *(u32*)&sh[r * RS + 2 * c] = hu[(size_t)gr * KU + c];
  }
  for (int i = tid; i < 64 * ZU; i += 256) {   // K-tail zeros
    int r = i / ZU, c = i - r * ZU;
    *(u32*)&sh[r * RS + K + 2 * c] = 0u;
  }
  __syncthreads();

  f32x4 acc[NT];
  #pragma unroll
  for (int ct = 0; ct < NT; ++ct) acc[ct] = f32x4{0.f, 0.f, 0.f, 0.f};

  const u16* abase = &sh[(wave * 16 + (lane & 15)) * RS + (lane >> 4) * 8];
  const short8* wb = (const short8*)Wp;

  short8 a = *(const short8*)abase;
  #pragma unroll 1
  for (int ks = 0; ks < KS; ++ks) {
    short8 an = (ks + 1 < KS) ? *(const short8*)(abase + (ks + 1) * 32) : a;
    #pragma unroll
    for (int ct = 0; ct < NT; ++ct) {
      short8 b = wb[(ks * NT + ct) * 64 + lane];
      acc[ct] = __builtin_amdgcn_mfma_f32_16x16x32_bf16(a, b, acc[ct], 0, 0, 0);
    }
    a = an;
  }

  // C/D layout: col = lane&15, row = (lane>>4)*4 + j   [m89-verified]
  int grow = rows0 + wave * 16 + ((lane >> 4) << 2);
  int cbase = lane & 15;

  float ps0[4] = {0, 0, 0, 0}, ps1[4] = {0, 0, 0, 0};
  float pd0[4] = {0, 0, 0, 0}, pd1[4] = {0, 0, 0, 0};
  #pragma unroll
  for (int ct = 0; ct < NT; ++ct) {
    int col = ct * 16 + cbase;
    bool valid = col < HC;
    bool head0 = col < CC;
    float as_v = valid ? a_s[col] : 0.f;
    float ad_v = valid ? a_d[col] : 0.f;
    #pragma unroll
    for (int j = 0; j < 4; ++j) {
      float v = acc[ct][j];
      int gr = grow + j;
      if (valid && gr < NN) hpb[(size_t)gr * HC + col] = f2bf(v);
      if (head0) { ps0[j] += v * as_v; pd0[j] += v * ad_v; }
      else       { ps1[j] += v * as_v; pd1[j] += v * ad_v; }
    }
  }
  // reduce across the 16 lanes of each row group
  #pragma unroll
  for (int o = 1; o < 16; o <<= 1) {
    #pragma unroll
    for (int j = 0; j < 4; ++j) {
      ps0[j] += __shfl_xor(ps0[j], o, 64);
      ps1[j] += __shfl_xor(ps1[j], o, 64);
      pd0[j] += __shfl_xor(pd0[j], o, 64);
      pd1[j] += __shfl_xor(pd1[j], o, 64);
    }
  }
  if ((lane & 15) == 0) {
    #pragma unroll
    for (int j = 0; j < 4; ++j) {
      int gr = grow + j;
      if (gr < NN) {
        ((float2*)al_s)[gr] = make_float2(ps0[j], ps1[j]);
        ((float2*)al_d)[gr] = make_float2(pd0[j], pd1[j]);
      }
    }
  }
}

__device__ __forceinline__ float lrelu(float v, float sl) {
  return v >= 0.f ? v : sl * v;
}

__device__ __forceinline__ void sm_combine(float& m, float& s, float om, float os) {
  if (om > m) {
    s = s * expf(m - om) + os;
    m = om;
  } else if (os > 0.f) {
    s += os * expf(om - m);
  }
}

// ---------------------------------------------------------------------------
// k_stats_alpha: per-node online-softmax stats, then per-edge alpha writeback.
// One wave per node. alpha2[slot] = {a0, a1} final normalized weights.
// ---------------------------------------------------------------------------
__global__ __launch_bounds__(256) void k_stats_alpha(
    const float* __restrict__ al_s, const float* __restrict__ al_d,
    const int* __restrict__ offsets, const int* __restrict__ csr_src,
    float2* __restrict__ alpha2) {
  int node = blockIdx.x * 4 + (threadIdx.x >> 6);
  int lane = threadIdx.x & 63;
  if (node >= NN) return;
  int off = offsets[node];
  int deg = offsets[node + 1] - off;
  const float2* al2 = (const float2*)al_s;
  float2 aldv = ((const float2*)al_d)[node];
  float ald0 = aldv.x, ald1 = aldv.y;

  float m0 = -INFINITY, s0 = 0.f, m1 = -INFINITY, s1 = 0.f;
  for (int i = lane; i < deg; i += 64) {
    int sn = csr_src[off + i];
    float2 av = al2[sn];
    float e0 = lrelu(av.x + ald0, 0.2f);
    float e1 = lrelu(av.y + ald1, 0.2f);
    if (e0 > m0) { s0 = s0 * expf(m0 - e0) + 1.f; m0 = e0; } else s0 += expf(e0 - m0);
    if (e1 > m1) { s1 = s1 * expf(m1 - e1) + 1.f; m1 = e1; } else s1 += expf(e1 - m1);
  }
  #pragma unroll
  for (int o = 32; o > 0; o >>= 1) {
    float om0 = __shfl_xor(m0, o, 64), os0 = __shfl_xor(s0, o, 64);
    float om1 = __shfl_xor(m1, o, 64), os1 = __shfl_xor(s1, o, 64);
    sm_combine(m0, s0, om0, os0);
    sm_combine(m1, s1, om1, os1);
  }
  float inv0 = 1.f / s0, inv1 = 1.f / s1;

  for (int i = lane; i < deg; i += 64) {
    int sn = csr_src[off + i];
    float2 av = al2[sn];          // L1/L2 hit (just gathered)
    float e0 = lrelu(av.x + ald0, 0.2f);
    float e1 = lrelu(av.y + ald1, 0.2f);
    alpha2[off + i] = make_float2(expf(e0 - m0) * inv0, expf(e1 - m1) * inv1);
  }
}

// ---------------------------------------------------------------------------
// pass B: weighted bf16-row aggregation; alpha precomputed.
// 4-deep software pipeline (chunks of 4 edges, A/B double-buffered bodies,
// all register indices static). Padding slots carry alpha=0 -> contribute 0.
// Lane j owns cols 4j..4j+3 (uint2 = 4 bf16) and cols 256+4j.. for j<11.
// ---------------------------------------------------------------------------
#define AGG_LOAD(SLOT, IDX, U, UT, AL)                                   \
  {                                                                      \
    int i_ = (IDX);                                                      \
    if (i_ < deg) {                                                      \
      int sn_ = csr_src[off + i_];                                       \
      AL[SLOT] = alpha2[off + i_];                                       \
      const uint2* rp_ = (const uint2*)(hpb + (size_t)sn_ * HC);         \
      U[SLOT] = rp_[lane];                                               \
      UT[SLOT] = hi ? rp_[64 + lane] : make_uint2(0u, 0u);               \
    } else {                                                             \
      AL[SLOT] = make_float2(0.f, 0.f);                                  \
      U[SLOT] = make_uint2(0u, 0u);                                      \
      UT[SLOT] = make_uint2(0u, 0u);                                     \
    }                                                                    \
  }

#define AGG_MATH(SLOT, U, UT, AL)                                        \
  {                                                                      \
    float a0_ = AL[SLOT].x, a1_ = AL[SLOT].y;                            \
    o0.x += bflo(U[SLOT].x) * (t0 ? a0_ : a1_);                          \
    o0.y += bfhi(U[SLOT].x) * (t1 ? a0_ : a1_);                          \
    o0.z += bflo(U[SLOT].y) * (t2 ? a0_ : a1_);                          \
    o0.w += bfhi(U[SLOT].y) * (t3 ? a0_ : a1_);                          \
    o1.x += bflo(UT[SLOT].x) * a1_;                                      \
    o1.y += bfhi(UT[SLOT].x) * a1_;                                      \
    o1.z += bflo(UT[SLOT].y) * a1_;                                      \
    o1.w += bfhi(UT[SLOT].y) * a1_;                                      \
  }

__device__ __forceinline__ void agg_b(
    const u16* __restrict__ hpb, const int* __restrict__ csr_src,
    const float2* __restrict__ alpha2, int off, int deg, int lane,
    float4& o0, float4& o1) {
  o0 = make_float4(0.f, 0.f, 0.f, 0.f);
  o1 = make_float4(0.f, 0.f, 0.f, 0.f);
  int c0 = lane * 4;
  bool t0 = c0 + 0 < CC, t1 = c0 + 1 < CC, t2 = c0 + 2 < CC, t3 = c0 + 3 < CC;
  bool hi = lane < 11;

  uint2 uA[4], utA[4]; float2 alA[4];
  uint2 uB[4], utB[4]; float2 alB[4];

  // prologue: chunk 0 -> A
  #pragma unroll
  for (int s = 0; s < 4; ++s) AGG_LOAD(s, s, uA, utA, alA);

  int base = 0;
  while (true) {
    // issue loads for next chunk into B, then consume A
    #pragma unroll
    for (int s = 0; s < 4; ++s) AGG_LOAD(s, base + 4 + s, uB, utB, alB);
    #pragma unroll
    for (int s = 0; s < 4; ++s) AGG_MATH(s, uA, utA, alA);
    base += 4;
    if (base >= deg) break;

    // issue loads for next chunk into A, then consume B
    #pragma unroll
    for (int s = 0; s < 4; ++s) AGG_LOAD(s, base + 4 + s, uA, utA, alA);
    #pragma unroll
    for (int s = 0; s < 4; ++s) AGG_MATH(s, uB, utB, alB);
    base += 4;
    if (base >= deg) break;
  }
}

// ---------------------------------------------------------------------------
// k_agg_ln: layer-1 pass B + bias + LayerNorm + leaky(0.01) -> h1b (bf16)
// ---------------------------------------------------------------------------
__global__ __launch_bounds__(256) void k_agg_ln(
    const u16* __restrict__ hpb, const int* __restrict__ offsets,
    const int* __restrict__ csr_src, const float2* __restrict__ alpha2,
    const float* __restrict__ b1, const float* __restrict__ ln_g,
    const float* __restrict__ ln_b, u16* __restrict__ h1b) {
  int node = blockIdx.x * 4 + (threadIdx.x >> 6);
  int lane = threadIdx.x & 63;
  if (node >= NN) return;
  int off = offsets[node];
  int deg = offsets[node + 1] - off;

  float4 o0, o1;
  agg_b(hpb, csr_src, alpha2, off, deg, lane, o0, o1);

  const float4* b14 = (const float4*)b1;
  float4 bb = b14[lane];
  o0.x += bb.x; o0.y += bb.y; o0.z += bb.z; o0.w += bb.w;
  if (lane < 11) {
    float4 bc = b14[64 + lane];
    o1.x += bc.x; o1.y += bc.y; o1.z += bc.z; o1.w += bc.w;
  }
  float part = o0.x + o0.y + o0.z + o0.w;
  if (lane < 11) part += o1.x + o1.y + o1.z + o1.w;
  #pragma unroll
  for (int o = 32; o > 0; o >>= 1) part += __shfl_xor(part, o, 64);
  float mu = part * (1.f / HC);
  float vp = (o0.x - mu) * (o0.x - mu) + (o0.y - mu) * (o0.y - mu) +
             (o0.z - mu) * (o0.z - mu) + (o0.w - mu) * (o0.w - mu);
  if (lane < 11)
    vp += (o1.x - mu) * (o1.x - mu) + (o1.y - mu) * (o1.y - mu) +
          (o1.z - mu) * (o1.z - mu) + (o1.w - mu) * (o1.w - mu);
  #pragma unroll
  for (int o = 32; o > 0; o >>= 1) vp += __shfl_xor(vp, o, 64);
  float rstd = 1.f / sqrtf(vp * (1.f / HC) + LN_EPS);

  const float4* g4 = (const float4*)ln_g;
  const float4* lb4 = (const float4*)ln_b;
  u32* h1u = (u32*)(h1b + (size_t)node * HC);
  float4 g = g4[lane], lb = lb4[lane];
  float wx = lrelu((o0.x - mu) * rstd * g.x + lb.x, 0.01f);
  float wy = lrelu((o0.y - mu) * rstd * g.y + lb.y, 0.01f);
  float wz = lrelu((o0.z - mu) * rstd * g.z + lb.z, 0.01f);
  float ww = lrelu((o0.w - mu) * rstd * g.w + lb.w, 0.01f);
  h1u[2 * lane + 0] = (u32)f2bf(wx) | ((u32)f2bf(wy) << 16);
  h1u[2 * lane + 1] = (u32)f2bf(wz) | ((u32)f2bf(ww) << 16);
  if (lane < 11) {
    float4 g1 = g4[64 + lane], lb1 = lb4[64 + lane];
    float vx = lrelu((o1.x - mu) * rstd * g1.x + lb1.x, 0.01f);
    float vy = lrelu((o1.y - mu) * rstd * g1.y + lb1.y, 0.01f);
    float vz = lrelu((o1.z - mu) * rstd * g1.z + lb1.z, 0.01f);
    float vw = lrelu((o1.w - mu) * rstd * g1.w + lb1.w, 0.01f);
    h1u[2 * (64 + lane) + 0] = (u32)f2bf(vx) | ((u32)f2bf(vy) << 16);
    h1u[2 * (64 + lane) + 1] = (u32)f2bf(vz) | ((u32)f2bf(vw) << 16);
  }
}

// ---------------------------------------------------------------------------
// k_agg_fc: layer-2 pass B + bias + leaky(0.01) + fc projection -> out (f32)
// ---------------------------------------------------------------------------
__global__ __launch_bounds__(256) void k_agg_fc(
    const u16* __restrict__ hpb, const int* __restrict__ offsets,
    const int* __restrict__ csr_src, const float2* __restrict__ alpha2,
    const float* __restrict__ b2, const float* __restrict__ fc_w,
    const float* __restrict__ fc_b, float* __restrict__ outp) {
  int node = blockIdx.x * 4 + (threadIdx.x >> 6);
  int lane = threadIdx.x & 63;
  if (node >= NN) return;
  int off = offsets[node];
  int deg = offsets[node + 1] - off;

  float4 o0, o1;
  agg_b(hpb, csr_src, alpha2, off, deg, lane, o0, o1);

  const float4* b24 = (const float4*)b2;
  const float4* f4 = (const float4*)fc_w;
  float4 bb = b24[lane], fw = f4[lane];
  float acc = lrelu(o0.x + bb.x, 0.01f) * fw.x +
              lrelu(o0.y + bb.y, 0.01f) * fw.y +
              lrelu(o0.z + bb.z, 0.01f) * fw.z +
              lrelu(o0.w + bb.w, 0.01f) * fw.w;
  if (lane < 11) {
    float4 bc = b24[64 + lane], fc = f4[64 + lane];
    acc += lrelu(o1.x + bc.x, 0.01f) * fc.x +
           lrelu(o1.y + bc.y, 0.01f) * fc.y +
           lrelu(o1.z + bc.z, 0.01f) * fc.z +
           lrelu(o1.w + bc.w, 0.01f) * fc.w;
  }
  #pragma unroll
  for (int o = 32; o > 0; o >>= 1) acc += __shfl_xor(acc, o, 64);
  if (lane == 0) outp[node] = acc + fc_b[0];
}

// ---------------------------------------------------------------------------
static inline size_t align_up(size_t x, size_t a) { return (x + a - 1) & ~(a - 1); }

extern "C" void kernel_launch(void* const* d_in, const int* in_sizes, int n_in,
                              void* d_out, int out_size, void* d_ws, size_t ws_size,
                              hipStream_t stream) {
  const float* x    = (const float*)d_in[0];
  const int*   ei   = (const int*)d_in[1];
  // d_in[2] edge_weight: unused by reference
  const float* emb  = (const float*)d_in[3];
  const float* W1   = (const float*)d_in[4];
  const float* as1  = (const float*)d_in[5];
  const float* ad1  = (const float*)d_in[6];
  const float* b1   = (const float*)d_in[7];
  const float* ln_g = (const float*)d_in[8];
  const float* ln_b = (const float*)d_in[9];
  const float* W2   = (const float*)d_in[10];
  const float* as2  = (const float*)d_in[11];
  const float* ad2  = (const float*)d_in[12];
  const float* b2   = (const float*)d_in[13];
  const float* fc_w = (const float*)d_in[14];
  const float* fc_b = (const float*)d_in[15];
  float* outp = (float*)d_out;

  constexpr int KS1 = (DD + 31) / 32;   // 5
  constexpr int KS2 = (HC + 31) / 32;   // 10

  // workspace layout
  char* ws = (char*)d_ws;
  size_t o = 0;
  size_t o_hpb = o; o = align_up(o + (size_t)NN * HC * 2, 256);   // 30 MB bf16
  size_t o_h1b = o; o = align_up(o + (size_t)NN * HC * 2, 256);   // 30 MB (h0b aliases)
  size_t o_als = o; o = align_up(o + (size_t)NN * 2 * 4, 256);
  size_t o_ald = o; o = align_up(o + (size_t)NN * 2 * 4, 256);
  size_t o_alp = o; o = align_up(o + (size_t)ET * 8, 256);        // 6.8 MB
  size_t o_cnt = o; o = align_up(o + (size_t)NN * 4, 256);
  size_t o_cur = o; o = align_up(o + (size_t)NN * 4, 256);
  size_t o_off = o; o = align_up(o + (size_t)(NN + 1) * 4, 256);
  size_t o_csr = o; o = align_up(o + (size_t)ET * 4, 256);
  size_t o_wp1 = o; o = align_up(o + (size_t)KS1 * NT * 64 * 8 * 2, 256);
  size_t o_wp2 = o; o = align_up(o + (size_t)KS2 * NT * 64 * 8 * 2, 256);

  u16*   hpb     = (u16*)(ws + o_hpb);
  u16*   h1b     = (u16*)(ws + o_h1b);
  u16*   h0b     = (u16*)(ws + o_h1b);  // alias: h0 dead before h1 written
  float* al_s    = (float*)(ws + o_als);
  float* al_d    = (float*)(ws + o_ald);
  float2* alpha2 = (float2*)(ws + o_alp);
  int*   counts  = (int*)(ws + o_cnt);
  int*   cursor  = (int*)(ws + o_cur);
  int*   offsets = (int*)(ws + o_off);
  int*   csr_src = (int*)(ws + o_csr);
  u16*   Wp1     = (u16*)(ws + o_wp1);
  u16*   Wp2     = (u16*)(ws + o_wp2);

  hipMemsetAsync(ws + o_cnt, 0, o_off - o_cnt, stream);  // counts + cursor

  const int nwave_blocks = (NN + 3) / 4;          // 12500
  const int edge_blocks  = (ET + 255) / 256;      // 3321
  const int gemm_blocks  = (NN + 63) / 64;        // 782

  // embedding gather + CSR build + weight prep
  k_argmax_embed<<<nwave_blocks, 256, 0, stream>>>(x, emb, h0b);
  k_count<<<edge_blocks, 256, 0, stream>>>(ei, counts);
  k_scan<<<1, 1024, 0, stream>>>(counts, offsets);
  k_scatter<<<edge_blocks, 256, 0, stream>>>(ei, offsets, cursor, csr_src);
  k_pack_w<<<KS1 * NT, 64, 0, stream>>>(W1, Wp1, DD);
  k_pack_w<<<KS2 * NT, 64, 0, stream>>>(W2, Wp2, HC);

  // ---- layer 1 ----
  k_gemm_mfma<DD><<<gemm_blocks, 256, 0, stream>>>(h0b, Wp1, as1, ad1,
                                                   hpb, al_s, al_d);
  k_stats_alpha<<<nwave_blocks, 256, 0, stream>>>(al_s, al_d, offsets,
                                                  csr_src, alpha2);
  k_agg_ln<<<nwave_blocks, 256, 0, stream>>>(hpb, offsets, csr_src, alpha2,
                                             b1, ln_g, ln_b, h1b);

  // ---- layer 2 ----
  k_gemm_mfma<HC><<<gemm_blocks, 256, 0, stream>>>(h1b, Wp2, as2, ad2,
                                                   hpb, al_s, al_d);
  k_stats_alpha<<<nwave_blocks, 256, 0, stream>>>(al_s, al_d, offsets,
                                                  csr_src, alpha2);
  k_agg_fc<<<nwave_blocks, 256, 0, stream>>>(hpb, offsets, csr_src, alpha2,
                                             b2, fc_w, fc_b, outp);
}

// Round 9
// 613.959 us; speedup vs baseline: 1.2374x; 1.2374x over previous
//
#include <hip/hip_runtime.h>
#include <hip/hip_bf16.h>
#include <math.h>

// Problem constants (from reference)
#define NN 50000
#define EE 800000
#define FIN 256
#define DD 150
#define HC 300        // H*C
#define CC 150
#define ET (EE + NN)  // edges + self loops = 850000
#define LN_EPS 1e-5f
#define NT 19         // col tiles of 16 covering 300 (304)
#define NB 49         // scan blocks: 49*1024 = 50176 >= NN

typedef __attribute__((ext_vector_type(8))) short short8;   // 8 bf16 (4 VGPR)
typedef __attribute__((ext_vector_type(4))) float f32x4;    // MFMA C/D frag
typedef unsigned short u16;
typedef unsigned int u32;

static __device__ __forceinline__ u16 f2bf(float f) {
  u32 u = __float_as_uint(f);
  u += 0x7FFFu + ((u >> 16) & 1u);   // round-to-nearest-even
  return (u16)(u >> 16);
}
static __device__ __forceinline__ float bflo(u32 u) {
  return __uint_as_float(u << 16);
}
static __device__ __forceinline__ float bfhi(u32 u) {
  return __uint_as_float(u & 0xFFFF0000u);
}

// ---------------------------------------------------------------------------
// k1: idx = argmax(x, axis=1); h0b = bf16(emb[idx])   (one wave per node)
// ---------------------------------------------------------------------------
__global__ __launch_bounds__(256) void k_argmax_embed(
    const float* __restrict__ x, const float* __restrict__ emb,
    u16* __restrict__ h0b) {
  int node = blockIdx.x * 4 + (threadIdx.x >> 6);
  int lane = threadIdx.x & 63;
  if (node >= NN) return;
  const float* row = x + (size_t)node * FIN;
  float best = -INFINITY;
  int bidx = FIN;
  #pragma unroll
  for (int r = 0; r < FIN / 64; ++r) {
    int j = lane + 64 * r;
    float v = row[j];
    if (v > best || (v == best && j < bidx)) { best = v; bidx = j; }
  }
  #pragma unroll
  for (int off = 32; off > 0; off >>= 1) {
    float ov = __shfl_xor(best, off, 64);
    int   oi = __shfl_xor(bidx, off, 64);
    if (ov > best || (ov == best && oi < bidx)) { best = ov; bidx = oi; }
  }
  // 150 f32 -> 75 uints of 2 bf16
  const float2* e2 = (const float2*)(emb + (size_t)bidx * DD);
  u32* o = (u32*)(h0b + (size_t)node * DD);
  float2 v = e2[lane];
  o[lane] = (u32)f2bf(v.x) | ((u32)f2bf(v.y) << 16);
  if (lane < 11) {
    float2 w = e2[64 + lane];
    o[64 + lane] = (u32)f2bf(w.x) | ((u32)f2bf(w.y) << 16);
  }
}

// ---------------------------------------------------------------------------
// CSR build: count -> (part / scan_part / scan_apply) -> scatter
// ---------------------------------------------------------------------------
__global__ __launch_bounds__(256) void k_count(
    const int* __restrict__ ei, int* __restrict__ counts) {
  int et = blockIdx.x * blockDim.x + threadIdx.x;
  if (et >= ET) return;
  int d = (et < EE) ? ei[EE + et] : (et - EE);
  atomicAdd(&counts[d], 1);
}

// per-block (1024-wide) sums of counts, coalesced
__global__ __launch_bounds__(1024) void k_part(
    const int* __restrict__ counts, int* __restrict__ partial) {
  __shared__ int red[1024];
  int tid = threadIdx.x;
  int i = blockIdx.x * 1024 + tid;
  red[tid] = (i < NN) ? counts[i] : 0;
  __syncthreads();
  for (int off = 512; off > 0; off >>= 1) {
    if (tid < off) red[tid] += red[tid + off];
    __syncthreads();
  }
  if (tid == 0) partial[blockIdx.x] = red[0];
}

// exclusive scan of the NB partials (one wave)
__global__ __launch_bounds__(64) void k_scan_part(
    const int* __restrict__ partial, int* __restrict__ pexc) {
  int t = threadIdx.x;
  int v = (t < NB) ? partial[t] : 0;
  int incl = v;
  #pragma unroll
  for (int off = 1; off < 64; off <<= 1) {
    int n = __shfl_up(incl, off, 64);
    if (t >= off) incl += n;
  }
  if (t < NB) pexc[t] = incl - v;
}

// block-level inclusive scan + partial prefix -> exclusive offsets
__global__ __launch_bounds__(1024) void k_scan_apply(
    const int* __restrict__ counts, const int* __restrict__ pexc,
    int* __restrict__ offsets) {
  __shared__ int buf[1024];
  int b = blockIdx.x, tid = threadIdx.x;
  int i = b * 1024 + tid;
  int v = (i < NN) ? counts[i] : 0;
  buf[tid] = v;
  __syncthreads();
  int incl = v;
  for (int off = 1; off < 1024; off <<= 1) {
    int t = (tid >= off) ? buf[tid - off] : 0;
    __syncthreads();
    incl += t;
    buf[tid] = incl;
    __syncthreads();
  }
  if (i <= NN) offsets[i] = pexc[b] + incl - v;  // i==NN lands here (v=0) -> ET
}

__global__ __launch_bounds__(256) void k_scatter(
    const int* __restrict__ ei, const int* __restrict__ offsets,
    int* __restrict__ cursor, int* __restrict__ csr_src) {
  int et = blockIdx.x * blockDim.x + threadIdx.x;
  if (et >= ET) return;
  int s = (et < EE) ? ei[et] : (et - EE);
  int d = (et < EE) ? ei[EE + et] : (et - EE);
  int pos = offsets[d] + atomicAdd(&cursor[d], 1);
  csr_src[pos] = s;
}

// ---------------------------------------------------------------------------
// k_pack_w: W [K][300] f32 -> Wp bf16 B-fragment layout [ks][ct][lane][8]
// Wp[((ks*NT+ct)*64+l)*8 + j] = W[ks*32+(l>>4)*8+j][ct*16+(l&15)]
// ---------------------------------------------------------------------------
__global__ __launch_bounds__(64) void k_pack_w(
    const float* __restrict__ W, u16* __restrict__ Wp, int K) {
  int ks = blockIdx.x / NT, ct = blockIdx.x % NT;
  int l = threadIdx.x;
  int col = ct * 16 + (l & 15);
  int kb = ks * 32 + ((l >> 4) << 3);
  u16 v[8];
  #pragma unroll
  for (int j = 0; j < 8; ++j) {
    int k = kb + j;
    float f = (k < K && col < HC) ? W[(size_t)k * HC + col] : 0.f;
    v[j] = f2bf(f);
  }
  *(ulonglong2*)(Wp + ((size_t)blockIdx.x * 64 + l) * 8) = *(ulonglong2*)v;
}

// ---------------------------------------------------------------------------
// k_gemm_mfma: hp(bf16) = h(bf16) @ W via mfma_f32_16x16x32_bf16, with fused
// attention-coefficient epilogue writing al_s/al_d (f32, from f32 acc).
// Block 256 = 4 waves, 64 rows/block; wave w -> rows [w*16, w*16+16).
// ---------------------------------------------------------------------------
template <int K>
__global__ __launch_bounds__(256) void k_gemm_mfma(
    const u16* __restrict__ h, const u16* __restrict__ Wp,
    const float* __restrict__ a_s, const float* __restrict__ a_d,
    u16* __restrict__ hpb, float* __restrict__ al_s,
    float* __restrict__ al_d) {
  constexpr int KS = (K + 31) / 32;
  constexpr int RS = KS * 32 + 8;     // +8 shorts pad
  constexpr int KU = K / 2;           // uints per row (K even)
  constexpr int ZU = (KS * 32 - K) / 2;
  __shared__ u16 sh[64 * RS];
  int tid = threadIdx.x;
  int wave = tid >> 6, lane = tid & 63;
  int rows0 = blockIdx.x * 64;

  // stage h (already bf16) -> LDS
  const u32* hu = (const u32*)h;
  for (int i = tid; i < 64 * KU; i += 256) {
    int r = i / KU, c = i - r * KU;
    int gr = rows0 + r; if (gr >= NN) gr = NN - 1;
    *(u32*)&sh[r * RS + 2 * c] = hu[(size_t)gr * KU + c];
  }
  for (int i = tid; i < 64 * ZU; i += 256) {   // K-tail zeros
    int r = i / ZU, c = i - r * ZU;
    *(u32*)&sh[r * RS + K + 2 * c] = 0u;
  }
  __syncthreads();

  f32x4 acc[NT];
  #pragma unroll
  for (int ct = 0; ct < NT; ++ct) acc[ct] = f32x4{0.f, 0.f, 0.f, 0.f};

  const u16* abase = &sh[(wave * 16 + (lane & 15)) * RS + (lane >> 4) * 8];
  const short8* wb = (const short8*)Wp;

  short8 a = *(const short8*)abase;
  #pragma unroll 1
  for (int ks = 0; ks < KS; ++ks) {
    short8 an = (ks + 1 < KS) ? *(const short8*)(abase + (ks + 1) * 32) : a;
    #pragma unroll
    for (int ct = 0; ct < NT; ++ct) {
      short8 b = wb[(ks * NT + ct) * 64 + lane];
      acc[ct] = __builtin_amdgcn_mfma_f32_16x16x32_bf16(a, b, acc[ct], 0, 0, 0);
    }
    a = an;
  }

  // C/D layout: col = lane&15, row = (lane>>4)*4 + j   [m89-verified]
  int grow = rows0 + wave * 16 + ((lane >> 4) << 2);
  int cbase = lane & 15;

  float ps0[4] = {0, 0, 0, 0}, ps1[4] = {0, 0, 0, 0};
  float pd0[4] = {0, 0, 0, 0}, pd1[4] = {0, 0, 0, 0};
  #pragma unroll
  for (int ct = 0; ct < NT; ++ct) {
    int col = ct * 16 + cbase;
    bool valid = col < HC;
    bool head0 = col < CC;
    float as_v = valid ? a_s[col] : 0.f;
    float ad_v = valid ? a_d[col] : 0.f;
    #pragma unroll
    for (int j = 0; j < 4; ++j) {
      float v = acc[ct][j];
      int gr = grow + j;
      if (valid && gr < NN) hpb[(size_t)gr * HC + col] = f2bf(v);
      if (head0) { ps0[j] += v * as_v; pd0[j] += v * ad_v; }
      else       { ps1[j] += v * as_v; pd1[j] += v * ad_v; }
    }
  }
  // reduce across the 16 lanes of each row group
  #pragma unroll
  for (int o = 1; o < 16; o <<= 1) {
    #pragma unroll
    for (int j = 0; j < 4; ++j) {
      ps0[j] += __shfl_xor(ps0[j], o, 64);
      ps1[j] += __shfl_xor(ps1[j], o, 64);
      pd0[j] += __shfl_xor(pd0[j], o, 64);
      pd1[j] += __shfl_xor(pd1[j], o, 64);
    }
  }
  if ((lane & 15) == 0) {
    #pragma unroll
    for (int j = 0; j < 4; ++j) {
      int gr = grow + j;
      if (gr < NN) {
        ((float2*)al_s)[gr] = make_float2(ps0[j], ps1[j]);
        ((float2*)al_d)[gr] = make_float2(pd0[j], pd1[j]);
      }
    }
  }
}

__device__ __forceinline__ float lrelu(float v, float sl) {
  return v >= 0.f ? v : sl * v;
}

__device__ __forceinline__ void sm_combine(float& m, float& s, float om, float os) {
  if (om > m) {
    s = s * expf(m - om) + os;
    m = om;
  } else if (os > 0.f) {
    s += os * expf(om - m);
  }
}

// ---------------------------------------------------------------------------
// k_stats_alpha: per-node online-softmax stats, then per-edge alpha writeback.
// One wave per node. alpha2[slot] = {a0, a1} final normalized weights.
// ---------------------------------------------------------------------------
__global__ __launch_bounds__(256) void k_stats_alpha(
    const float* __restrict__ al_s, const float* __restrict__ al_d,
    const int* __restrict__ offsets, const int* __restrict__ csr_src,
    float2* __restrict__ alpha2) {
  int node = blockIdx.x * 4 + (threadIdx.x >> 6);
  int lane = threadIdx.x & 63;
  if (node >= NN) return;
  int off = offsets[node];
  int deg = offsets[node + 1] - off;
  const float2* al2 = (const float2*)al_s;
  float2 aldv = ((const float2*)al_d)[node];
  float ald0 = aldv.x, ald1 = aldv.y;

  float m0 = -INFINITY, s0 = 0.f, m1 = -INFINITY, s1 = 0.f;
  for (int i = lane; i < deg; i += 64) {
    int sn = csr_src[off + i];
    float2 av = al2[sn];
    float e0 = lrelu(av.x + ald0, 0.2f);
    float e1 = lrelu(av.y + ald1, 0.2f);
    if (e0 > m0) { s0 = s0 * expf(m0 - e0) + 1.f; m0 = e0; } else s0 += expf(e0 - m0);
    if (e1 > m1) { s1 = s1 * expf(m1 - e1) + 1.f; m1 = e1; } else s1 += expf(e1 - m1);
  }
  #pragma unroll
  for (int o = 32; o > 0; o >>= 1) {
    float om0 = __shfl_xor(m0, o, 64), os0 = __shfl_xor(s0, o, 64);
    float om1 = __shfl_xor(m1, o, 64), os1 = __shfl_xor(s1, o, 64);
    sm_combine(m0, s0, om0, os0);
    sm_combine(m1, s1, om1, os1);
  }
  float inv0 = 1.f / s0, inv1 = 1.f / s1;

  for (int i = lane; i < deg; i += 64) {
    int sn = csr_src[off + i];
    float2 av = al2[sn];          // L1/L2 hit (just gathered)
    float e0 = lrelu(av.x + ald0, 0.2f);
    float e1 = lrelu(av.y + ald1, 0.2f);
    alpha2[off + i] = make_float2(expf(e0 - m0) * inv0, expf(e1 - m1) * inv1);
  }
}

// ---------------------------------------------------------------------------
// pass B: weighted bf16-row aggregation; alpha precomputed (1-deep prefetch —
// r6 form; 4-deep pipeline regressed (r7): gather is contention-bound).
// Lane j owns cols 4j..4j+3 (uint2 = 4 bf16) and cols 256+4j.. for j<11.
// ---------------------------------------------------------------------------
__device__ __forceinline__ void agg_b(
    const u16* __restrict__ hpb, const int* __restrict__ csr_src,
    const float2* __restrict__ alpha2, int off, int deg, int lane,
    float4& o0, float4& o1) {
  o0 = make_float4(0.f, 0.f, 0.f, 0.f);
  o1 = make_float4(0.f, 0.f, 0.f, 0.f);
  int c0 = lane * 4;
  bool t0 = c0 + 0 < CC, t1 = c0 + 1 < CC, t2 = c0 + 2 < CC, t3 = c0 + 3 < CC;
  bool hi = lane < 11;

  int sn = csr_src[off];
  float2 al = alpha2[off];
  const uint2* rp = (const uint2*)(hpb + (size_t)sn * HC);
  uint2 u = rp[lane];
  uint2 ut = make_uint2(0u, 0u);
  if (hi) ut = rp[64 + lane];

  for (int i = 0; i < deg; ++i) {
    float2 nal = make_float2(0.f, 0.f);
    uint2 nu = make_uint2(0u, 0u), nut = make_uint2(0u, 0u);
    if (i + 1 < deg) {            // prefetch next row
      int nsn = csr_src[off + i + 1];
      nal = alpha2[off + i + 1];
      const uint2* nrp = (const uint2*)(hpb + (size_t)nsn * HC);
      nu = nrp[lane];
      if (hi) nut = nrp[64 + lane];
    }
    float a0 = al.x, a1 = al.y;
    o0.x += bflo(u.x) * (t0 ? a0 : a1);
    o0.y += bfhi(u.x) * (t1 ? a0 : a1);
    o0.z += bflo(u.y) * (t2 ? a0 : a1);
    o0.w += bfhi(u.y) * (t3 ? a0 : a1);
    o1.x += bflo(ut.x) * a1;      // ut stays 0 for lane>=11
    o1.y += bfhi(ut.x) * a1;
    o1.z += bflo(ut.y) * a1;
    o1.w += bfhi(ut.y) * a1;
    u = nu; ut = nut; al = nal;
  }
}

// ---------------------------------------------------------------------------
// k_agg_ln: layer-1 pass B + bias + LayerNorm + leaky(0.01) -> h1b (bf16)
// ---------------------------------------------------------------------------
__global__ __launch_bounds__(256) void k_agg_ln(
    const u16* __restrict__ hpb, const int* __restrict__ offsets,
    const int* __restrict__ csr_src, const float2* __restrict__ alpha2,
    const float* __restrict__ b1, const float* __restrict__ ln_g,
    const float* __restrict__ ln_b, u16* __restrict__ h1b) {
  int node = blockIdx.x * 4 + (threadIdx.x >> 6);
  int lane = threadIdx.x & 63;
  if (node >= NN) return;
  int off = offsets[node];
  int deg = offsets[node + 1] - off;

  float4 o0, o1;
  agg_b(hpb, csr_src, alpha2, off, deg, lane, o0, o1);

  const float4* b14 = (const float4*)b1;
  float4 bb = b14[lane];
  o0.x += bb.x; o0.y += bb.y; o0.z += bb.z; o0.w += bb.w;
  if (lane < 11) {
    float4 bc = b14[64 + lane];
    o1.x += bc.x; o1.y += bc.y; o1.z += bc.z; o1.w += bc.w;
  }
  float part = o0.x + o0.y + o0.z + o0.w;
  if (lane < 11) part += o1.x + o1.y + o1.z + o1.w;
  #pragma unroll
  for (int o = 32; o > 0; o >>= 1) part += __shfl_xor(part, o, 64);
  float mu = part * (1.f / HC);
  float vp = (o0.x - mu) * (o0.x - mu) + (o0.y - mu) * (o0.y - mu) +
             (o0.z - mu) * (o0.z - mu) + (o0.w - mu) * (o0.w - mu);
  if (lane < 11)
    vp += (o1.x - mu) * (o1.x - mu) + (o1.y - mu) * (o1.y - mu) +
          (o1.z - mu) * (o1.z - mu) + (o1.w - mu) * (o1.w - mu);
  #pragma unroll
  for (int o = 32; o > 0; o >>= 1) vp += __shfl_xor(vp, o, 64);
  float rstd = 1.f / sqrtf(vp * (1.f / HC) + LN_EPS);

  const float4* g4 = (const float4*)ln_g;
  const float4* lb4 = (const float4*)ln_b;
  u32* h1u = (u32*)(h1b + (size_t)node * HC);
  float4 g = g4[lane], lb = lb4[lane];
  float wx = lrelu((o0.x - mu) * rstd * g.x + lb.x, 0.01f);
  float wy = lrelu((o0.y - mu) * rstd * g.y + lb.y, 0.01f);
  float wz = lrelu((o0.z - mu) * rstd * g.z + lb.z, 0.01f);
  float ww = lrelu((o0.w - mu) * rstd * g.w + lb.w, 0.01f);
  h1u[2 * lane + 0] = (u32)f2bf(wx) | ((u32)f2bf(wy) << 16);
  h1u[2 * lane + 1] = (u32)f2bf(wz) | ((u32)f2bf(ww) << 16);
  if (lane < 11) {
    float4 g1 = g4[64 + lane], lb1 = lb4[64 + lane];
    float vx = lrelu((o1.x - mu) * rstd * g1.x + lb1.x, 0.01f);
    float vy = lrelu((o1.y - mu) * rstd * g1.y + lb1.y, 0.01f);
    float vz = lrelu((o1.z - mu) * rstd * g1.z + lb1.z, 0.01f);
    float vw = lrelu((o1.w - mu) * rstd * g1.w + lb1.w, 0.01f);
    h1u[2 * (64 + lane) + 0] = (u32)f2bf(vx) | ((u32)f2bf(vy) << 16);
    h1u[2 * (64 + lane) + 1] = (u32)f2bf(vz) | ((u32)f2bf(vw) << 16);
  }
}

// ---------------------------------------------------------------------------
// k_agg_fc: layer-2 pass B + bias + leaky(0.01) + fc projection -> out (f32)
// ---------------------------------------------------------------------------
__global__ __launch_bounds__(256) void k_agg_fc(
    const u16* __restrict__ hpb, const int* __restrict__ offsets,
    const int* __restrict__ csr_src, const float2* __restrict__ alpha2,
    const float* __restrict__ b2, const float* __restrict__ fc_w,
    const float* __restrict__ fc_b, float* __restrict__ outp) {
  int node = blockIdx.x * 4 + (threadIdx.x >> 6);
  int lane = threadIdx.x & 63;
  if (node >= NN) return;
  int off = offsets[node];
  int deg = offsets[node + 1] - off;

  float4 o0, o1;
  agg_b(hpb, csr_src, alpha2, off, deg, lane, o0, o1);

  const float4* b24 = (const float4*)b2;
  const float4* f4 = (const float4*)fc_w;
  float4 bb = b24[lane], fw = f4[lane];
  float acc = lrelu(o0.x + bb.x, 0.01f) * fw.x +
              lrelu(o0.y + bb.y, 0.01f) * fw.y +
              lrelu(o0.z + bb.z, 0.01f) * fw.z +
              lrelu(o0.w + bb.w, 0.01f) * fw.w;
  if (lane < 11) {
    float4 bc = b24[64 + lane], fc = f4[64 + lane];
    acc += lrelu(o1.x + bc.x, 0.01f) * fc.x +
           lrelu(o1.y + bc.y, 0.01f) * fc.y +
           lrelu(o1.z + bc.z, 0.01f) * fc.z +
           lrelu(o1.w + bc.w, 0.01f) * fc.w;
  }
  #pragma unroll
  for (int o = 32; o > 0; o >>= 1) acc += __shfl_xor(acc, o, 64);
  if (lane == 0) outp[node] = acc + fc_b[0];
}

// ---------------------------------------------------------------------------
static inline size_t align_up(size_t x, size_t a) { return (x + a - 1) & ~(a - 1); }

extern "C" void kernel_launch(void* const* d_in, const int* in_sizes, int n_in,
                              void* d_out, int out_size, void* d_ws, size_t ws_size,
                              hipStream_t stream) {
  const float* x    = (const float*)d_in[0];
  const int*   ei   = (const int*)d_in[1];
  // d_in[2] edge_weight: unused by reference
  const float* emb  = (const float*)d_in[3];
  const float* W1   = (const float*)d_in[4];
  const float* as1  = (const float*)d_in[5];
  const float* ad1  = (const float*)d_in[6];
  const float* b1   = (const float*)d_in[7];
  const float* ln_g = (const float*)d_in[8];
  const float* ln_b = (const float*)d_in[9];
  const float* W2   = (const float*)d_in[10];
  const float* as2  = (const float*)d_in[11];
  const float* ad2  = (const float*)d_in[12];
  const float* b2   = (const float*)d_in[13];
  const float* fc_w = (const float*)d_in[14];
  const float* fc_b = (const float*)d_in[15];
  float* outp = (float*)d_out;

  constexpr int KS1 = (DD + 31) / 32;   // 5
  constexpr int KS2 = (HC + 31) / 32;   // 10

  // workspace layout
  char* ws = (char*)d_ws;
  size_t o = 0;
  size_t o_hpb = o; o = align_up(o + (size_t)NN * HC * 2, 256);   // 30 MB bf16
  size_t o_h1b = o; o = align_up(o + (size_t)NN * HC * 2, 256);   // 30 MB (h0b aliases)
  size_t o_als = o; o = align_up(o + (size_t)NN * 2 * 4, 256);
  size_t o_ald = o; o = align_up(o + (size_t)NN * 2 * 4, 256);
  size_t o_alp = o; o = align_up(o + (size_t)ET * 8, 256);        // 6.8 MB
  size_t o_cnt = o; o = align_up(o + (size_t)NN * 4, 256);
  size_t o_cur = o; o = align_up(o + (size_t)NN * 4, 256);
  size_t o_off = o; o = align_up(o + (size_t)(NN + 1) * 4, 256);
  size_t o_csr = o; o = align_up(o + (size_t)ET * 4, 256);
  size_t o_wp1 = o; o = align_up(o + (size_t)KS1 * NT * 64 * 8 * 2, 256);
  size_t o_wp2 = o; o = align_up(o + (size_t)KS2 * NT * 64 * 8 * 2, 256);
  size_t o_par = o; o = align_up(o + (size_t)NB * 4, 256);
  size_t o_pex = o; o = align_up(o + (size_t)(NB + 1) * 4, 256);

  u16*   hpb     = (u16*)(ws + o_hpb);
  u16*   h1b     = (u16*)(ws + o_h1b);
  u16*   h0b     = (u16*)(ws + o_h1b);  // alias: h0 dead before h1 written
  float* al_s    = (float*)(ws + o_als);
  float* al_d    = (float*)(ws + o_ald);
  float2* alpha2 = (float2*)(ws + o_alp);
  int*   counts  = (int*)(ws + o_cnt);
  int*   cursor  = (int*)(ws + o_cur);
  int*   offsets = (int*)(ws + o_off);
  int*   csr_src = (int*)(ws + o_csr);
  u16*   Wp1     = (u16*)(ws + o_wp1);
  u16*   Wp2     = (u16*)(ws + o_wp2);
  int*   partial = (int*)(ws + o_par);
  int*   pexc    = (int*)(ws + o_pex);

  hipMemsetAsync(ws + o_cnt, 0, o_off - o_cnt, stream);  // counts + cursor

  const int nwave_blocks = (NN + 3) / 4;          // 12500
  const int edge_blocks  = (ET + 255) / 256;      // 3321
  const int gemm_blocks  = (NN + 63) / 64;        // 782

  // embedding gather + CSR build + weight prep
  k_argmax_embed<<<nwave_blocks, 256, 0, stream>>>(x, emb, h0b);
  k_count<<<edge_blocks, 256, 0, stream>>>(ei, counts);
  k_part<<<NB, 1024, 0, stream>>>(counts, partial);
  k_scan_part<<<1, 64, 0, stream>>>(partial, pexc);
  k_scan_apply<<<NB, 1024, 0, stream>>>(counts, pexc, offsets);
  k_scatter<<<edge_blocks, 256, 0, stream>>>(ei, offsets, cursor, csr_src);
  k_pack_w<<<KS1 * NT, 64, 0, stream>>>(W1, Wp1, DD);
  k_pack_w<<<KS2 * NT, 64, 0, stream>>>(W2, Wp2, HC);

  // ---- layer 1 ----
  k_gemm_mfma<DD><<<gemm_blocks, 256, 0, stream>>>(h0b, Wp1, as1, ad1,
                                                   hpb, al_s, al_d);
  k_stats_alpha<<<nwave_blocks, 256, 0, stream>>>(al_s, al_d, offsets,
                                                  csr_src, alpha2);
  k_agg_ln<<<nwave_blocks, 256, 0, stream>>>(hpb, offsets, csr_src, alpha2,
                                             b1, ln_g, ln_b, h1b);

  // ---- layer 2 ----
  k_gemm_mfma<HC><<<gemm_blocks, 256, 0, stream>>>(h1b, Wp2, as2, ad2,
                                                   hpb, al_s, al_d);
  k_stats_alpha<<<nwave_blocks, 256, 0, stream>>>(al_s, al_d, offsets,
                                                  csr_src, alpha2);
  k_agg_fc<<<nwave_blocks, 256, 0, stream>>>(hpb, offsets, csr_src, alpha2,
                                             b2, fc_w, fc_b, outp);
}